// Round 5
// baseline (119.013 us; speedup 1.0000x reference)
//
#include <hip/hip_runtime.h>
#include <math.h>

#define BB 2
#define NN 512
#define DD 32
#define HH 64
#define JT 2
#define IPB 2
#define NBLK1 (BB*(NN/IPB)*JT)   // 1024
#define NBLK3 (BB*NN)            // 1024

// ws layout (float offsets)
#define SC_OFF  0                        // scores: B*N*N = 524288
#define MF_OFF  (SC_OFF + BB*NN*NN)      // 0.5*M B-frags: 4096 halves = 2048 fl
#define WF_OFF  (MF_OFF + 2048)          // 0.25*Ws1 B-frags: 2048 halves = 1024 fl
#define W1F_OFF (WF_OFF + 1024)          // W1/b1 A-table: 192 halves (pad 128 fl)
#define PM2_OFF (W1F_OFF + 128)          // per-pass1-block max: 1024
#define PS2_OFF (PM2_OFF + NBLK1)        // per-pass1-block sumexp: 1024
#define ST_OFF  (PS2_OFF + NBLK1)        // per-batch {max, inv_sum}: B*2
#define A_OFF   (ST_OFF + BB*2)          // A accumulator: B*64 = 128
#define CS_OFF  (A_OFF + BB*HH)          // col sums: B*N = 1024
#define TK_OFF  (CS_OFF + BB*NN)         // ticket (int, 1 slot)

typedef _Float16 half8 __attribute__((ext_vector_type(8)));
typedef float    f32x4 __attribute__((ext_vector_type(4)));

__device__ __forceinline__ half8 h8splat(float v) {
    _Float16 h = (_Float16)v;
    half8 r = {h,h,h,h,h,h,h,h};
    return r;
}

__device__ __forceinline__ void invar2(float pix, float piy, float piz,
                                       float pjx, float pjy, float pjz,
                                       float& s, float& cr) {
    s = pix*pjx + piy*pjy + piz*pjz;
    float e12 = pjx*piy - pjy*pix;
    float e13 = pjx*piz - pjz*pix;
    float e23 = pjy*piz - pjz*piy;
    cr = sqrtf(e12*e12 + e13*e13 + e23*e23);
}

// ---------------- prep-lite: fragment tables + zero accumulators ----------------
#define R2 4096                       // M frag halves
#define R3 2048                       // Ws1 frag halves
#define R4 192                        // W1/b1 table halves
#define RZ (BB*HH + BB*NN + 1)        // zeros: A, CS, ticket
#define PREP_T (R2+R3+R4+RZ)

__global__ __launch_bounds__(256) void prep(const float* __restrict__ W1,
                                            const float* __restrict__ b1,
                                            const float* __restrict__ W2,
                                            const float* __restrict__ Ws1,
                                            float* __restrict__ ws) {
    int idx = blockIdx.x * 256 + threadIdx.x;
    if (idx < R2) {
        // 0.5*(W2@Ws1) fragment: f=cf*2+kh; lane holds k=kh*32+8*(lane>>4)+t, col=cf*16+(lane&15)
        int e = idx;
        int t = e & 7, lane = (e >> 3) & 63, f = e >> 9;
        int cf = f >> 1, kh = f & 1;
        int k   = kh*32 + 8*(lane >> 4) + t;
        int col = cf*16 + (lane & 15);
        float acc = 0.f;
        #pragma unroll
        for (int d = 0; d < DD; d++) acc += W2[k*DD + d] * Ws1[d*HH + col];
        ((_Float16*)(ws + MF_OFF))[e] = (_Float16)(0.5f * acc);
    } else if (idx < R2+R3) {
        // 0.25*Ws1 fragment (K=32, k=d)
        int e = idx - R2;
        int t = e & 7, lane = (e >> 3) & 63, cf = e >> 9;
        int k   = 8*(lane >> 4) + t;
        int col = cf*16 + (lane & 15);
        ((_Float16*)(ws + WF_OFF))[e] = (_Float16)(0.25f * Ws1[k*HH + col]);
    } else if (idx < R2+R3+R4) {
        // W1/b1 table: e = ((arr*2+kh)*4+g)*8+t, k = kh*32+8g+t
        int e = idx - R2 - R3;
        int t = e & 7, rest = e >> 3;
        int g = rest & 3, kh = (rest >> 2) & 1, arr = rest >> 3;
        int k = kh*32 + 8*g + t;
        float v = (arr == 0) ? W1[k] : (arr == 1) ? W1[HH + k] : b1[k];
        ((_Float16*)(ws + W1F_OFF))[e] = (_Float16)v;
    } else if (idx < PREP_T) {
        int local = idx - (R2+R3+R4);
        if (local < BB*HH)            ws[A_OFF + local] = 0.f;
        else if (local < BB*HH+BB*NN) ws[CS_OFF + (local - BB*HH)] = 0.f;
        else                          *(int*)(ws + TK_OFF) = 0;
    }
}

// ---------------- pass1: scores via K=96 MFMA + fused softmax partials ----------------
// block = (b, i-pair, jt). 4 waves; wave w owns j in [jt*256+w*64, +64), 2 i rows each.
__global__ __launch_bounds__(256) void pass1(const float* __restrict__ pos,
                                             const float* __restrict__ values,
                                             const float* __restrict__ b2,
                                             const float* __restrict__ Ws1,
                                             const float* __restrict__ bs1,
                                             const float* __restrict__ Ws2,
                                             const float* __restrict__ bs2,
                                             float* __restrict__ ws) {
    __shared__ float uqc[IPB][HH];   // (0.25*v_i + 0.5*b2)@Ws1 + bs1
    __shared__ float ws2l[HH];
    __shared__ float sm4[4], ss4[4];
    int blk = blockIdx.x;
    int jt = blk & 1;
    int ip = (blk >> 1) & 255;
    int b  = blk >> 9;
    int i0 = ip * IPB;
    int tid = threadIdx.x;
    int w    = tid >> 6;
    int lane = tid & 63;
    int g    = lane >> 4;
    int lr   = lane & 15;

    if (tid < IPB*HH) {
        int ii = tid >> 6, l = tid & 63;
        const float* vrow = values + (size_t)(b*NN + i0 + ii)*DD;
        float acc = bs1[l];
        #pragma unroll
        for (int d = 0; d < DD; d++) acc += (0.25f*vrow[d] + 0.5f*b2[d]) * Ws1[d*HH + l];
        uqc[ii][l] = acc;
        if (ii == 0) ws2l[l] = Ws2[l];
    }

    // B fragments from ws (coalesced 16B/lane, L2-hit)
    const half8* mf8 = (const half8*)(ws + MF_OFF);
    const half8* wf8 = (const half8*)(ws + WF_OFF);
    half8 Bf[4][2], Wf[4];
    #pragma unroll
    for (int cf = 0; cf < 4; cf++) {
        Bf[cf][0] = mf8[(cf*2 + 0)*64 + lane];
        Bf[cf][1] = mf8[(cf*2 + 1)*64 + lane];
        Wf[cf]    = wf8[cf*64 + lane];
    }
    const half8* w1f8 = (const half8*)(ws + W1F_OFF);
    half8 W1a[2], W1b[2], B1f[2];
    #pragma unroll
    for (int kh = 0; kh < 2; kh++) {
        W1a[kh] = w1f8[(0*2 + kh)*4 + g];
        W1b[kh] = w1f8[(1*2 + kh)*4 + g];
        B1f[kh] = w1f8[(2*2 + kh)*4 + g];
    }

    float pix[IPB], piy[IPB], piz[IPB];
    #pragma unroll
    for (int ii = 0; ii < IPB; ii++) {
        pix[ii] = pos[(b*NN+i0+ii)*3+0];
        piy[ii] = pos[(b*NN+i0+ii)*3+1];
        piz[ii] = pos[(b*NN+i0+ii)*3+2];
    }
    float bs2v = bs2[0];
    half8 z8 = h8splat(0.f);

    __syncthreads();

    float m_run = -INFINITY, s_run = 0.f;

    #pragma unroll
    for (int rf = 0; rf < 4; rf++) {
        int j_a = jt*256 + w*64 + rf*16 + lr;
        float pjx = pos[(b*NN+j_a)*3+0], pjy = pos[(b*NN+j_a)*3+1], pjz = pos[(b*NN+j_a)*3+2];
        // A2 = f16(values[j_a][8g..8g+8])
        const float* vj = values + (size_t)(b*NN + j_a)*DD + 8*g;
        half8 A2;
        #pragma unroll
        for (int t = 0; t < 8; t++) A2[t] = (_Float16)vj[t];

        #pragma unroll
        for (int ii = 0; ii < IPB; ii++) {
            float s, cr;
            invar2(pix[ii],piy[ii],piz[ii],pjx,pjy,pjz,s,cr);
            half8 s8 = h8splat(s), c8 = h8splat(cr);
            half8 A0 = __builtin_elementwise_max(W1a[0]*s8 + W1b[0]*c8 + B1f[0], z8);
            half8 A1 = __builtin_elementwise_max(W1a[1]*s8 + W1b[1]*c8 + B1f[1], z8);

            f32x4 c[4];
            #pragma unroll
            for (int cf = 0; cf < 4; cf++) {
                f32x4 z = {0.f, 0.f, 0.f, 0.f};
                z = __builtin_amdgcn_mfma_f32_16x16x32_f16(A0, Bf[cf][0], z, 0, 0, 0);
                z = __builtin_amdgcn_mfma_f32_16x16x32_f16(A1, Bf[cf][1], z, 0, 0, 0);
                c[cf] = __builtin_amdgcn_mfma_f32_16x16x32_f16(A2, Wf[cf], z, 0, 0, 0);
            }

            float part0 = 0.f, part1 = 0.f, part2 = 0.f, part3 = 0.f;
            #pragma unroll
            for (int cf = 0; cf < 4; cf++) {
                int lc = cf*16 + lr;
                float base = uqc[ii][lc];
                float w2v  = ws2l[lc];
                part0 += fmaxf(c[cf][0] + base, 0.f) * w2v;
                part1 += fmaxf(c[cf][1] + base, 0.f) * w2v;
                part2 += fmaxf(c[cf][2] + base, 0.f) * w2v;
                part3 += fmaxf(c[cf][3] + base, 0.f) * w2v;
            }
            #pragma unroll
            for (int m = 1; m < 16; m <<= 1) {
                part0 += __shfl_xor(part0, m);
                part1 += __shfl_xor(part1, m);
                part2 += __shfl_xor(part2, m);
                part3 += __shfl_xor(part3, m);
            }
            float x0 = part0 + bs2v, x1 = part1 + bs2v, x2 = part2 + bs2v, x3 = part3 + bs2v;
            if (lr == 0) {
                float4 outv; outv.x = x0; outv.y = x1; outv.z = x2; outv.w = x3;
                *(float4*)(ws + SC_OFF + (size_t)(b*NN + i0 + ii)*NN + jt*256 + w*64 + rf*16 + 4*g) = outv;
            }
            float mm = fmaxf(fmaxf(x0, x1), fmaxf(x2, x3));
            float nm = fmaxf(m_run, mm);
            s_run = s_run*__expf(m_run - nm)
                  + __expf(x0 - nm) + __expf(x1 - nm) + __expf(x2 - nm) + __expf(x3 - nm);
            m_run = nm;
        }
    }

    #pragma unroll
    for (int off = 16; off < 64; off <<= 1) {
        float om = __shfl_xor(m_run, off);
        float os = __shfl_xor(s_run, off);
        float nm = fmaxf(m_run, om);
        s_run = s_run*__expf(m_run - nm) + os*__expf(om - nm);
        m_run = nm;
    }
    if (lane == 0) { sm4[w] = m_run; ss4[w] = s_run; }
    __syncthreads();
    if (tid == 0) {
        float M0 = sm4[0], S0 = ss4[0];
        #pragma unroll
        for (int q = 1; q < 4; q++) {
            float nm = fmaxf(M0, sm4[q]);
            S0 = S0*__expf(M0 - nm) + ss4[q]*__expf(sm4[q] - nm);
            M0 = nm;
        }
        ws[PM2_OFF + blk] = M0;
        ws[PS2_OFF + blk] = S0;
    }
}

// ---------------- midk: reduce 512 partials per batch -> ST ----------------
__global__ __launch_bounds__(256) void midk(float* __restrict__ ws) {
    __shared__ float red[8];
    int tid = threadIdx.x;
    int w = tid >> 6, lane = tid & 63;
    for (int b = 0; b < BB; b++) {
        float m = -INFINITY, s = 0.f;
        #pragma unroll
        for (int q = 0; q < 2; q++) {
            int p = b*512 + tid + q*256;
            float pm = ws[PM2_OFF + p], ps = ws[PS2_OFF + p];
            float nm = fmaxf(m, pm);
            s = s*__expf(m - nm) + ps*__expf(pm - nm);
            m = nm;
        }
        for (int off = 1; off < 64; off <<= 1) {
            float om = __shfl_xor(m, off);
            float os = __shfl_xor(s, off);
            float nm = fmaxf(m, om);
            s = s*__expf(m - nm) + os*__expf(om - nm);
            m = nm;
        }
        if (lane == 0) { red[w*2] = m; red[w*2+1] = s; }
        __syncthreads();
        if (tid == 0) {
            float M0 = red[0], S0 = red[1];
            #pragma unroll
            for (int q = 1; q < 4; q++) {
                float nm = fmaxf(M0, red[q*2]);
                S0 = S0*__expf(M0 - nm) + red[q*2+1]*__expf(red[q*2] - nm);
                M0 = nm;
            }
            ws[ST_OFF + b*2]     = M0;
            ws[ST_OFF + b*2 + 1] = 1.f / S0;
        }
        __syncthreads();
    }
}

// ---------------- pass3: block = (b,i) row; lane-owns-k accumulation ----------------
__global__ __launch_bounds__(256) void pass3(const float* __restrict__ pos,
                                             const float* __restrict__ values,
                                             const float* __restrict__ W1,
                                             const float* __restrict__ b1,
                                             const float* __restrict__ W2,
                                             const float* __restrict__ b2,
                                             float* __restrict__ ws,
                                             float* __restrict__ out) {
    __shared__ float sA[NN], cA[NN], wA[NN];   // 6 KB
    __shared__ float Aw[4][HH];
    __shared__ float fin[4*HH];
    __shared__ int lastf;
    int blk = blockIdx.x;          // 1024 = B*N
    int b = blk >> 9;
    int i = blk & (NN-1);
    int tid = threadIdx.x;
    int w = tid >> 6, lane = tid & 63;

    float maxv = ws[ST_OFF + b*2], inv = ws[ST_OFF + b*2 + 1];
    float pix = pos[(b*NN+i)*3+0], piy = pos[(b*NN+i)*3+1], piz = pos[(b*NN+i)*3+2];
    const float* sc_row = ws + SC_OFF + (size_t)(b*NN + i)*NN;

    // ---- phase A: pair-parallel wgt/s/cr -> LDS, cs atomics ----
    #pragma unroll
    for (int q = 0; q < 2; q++) {
        int j = tid + q*256;
        float pjx = pos[(b*NN+j)*3+0], pjy = pos[(b*NN+j)*3+1], pjz = pos[(b*NN+j)*3+2];
        float s, cr;
        invar2(pix,piy,piz,pjx,pjy,pjz,s,cr);
        float wgt = __expf(sc_row[j] - maxv) * inv;
        sA[j] = s; cA[j] = cr; wA[j] = wgt;
        atomicAdd(&ws[CS_OFF + b*NN + j], wgt);
    }

    // ---- phase B: lane owns k; wave walks 128 pairs with broadcast LDS reads ----
    float w1a = W1[lane], w1b = W1[HH + lane], b1l = b1[lane];
    __syncthreads();
    float Ak = 0.f;
    int p0 = w * 128;
    #pragma unroll 4
    for (int p = p0; p < p0 + 128; p++) {
        float s = sA[p], cr = cA[p], wgt = wA[p];
        float h = fmaxf(fmaf(w1a, s, fmaf(w1b, cr, b1l)), 0.f);
        Ak = fmaf(wgt, h, Ak);
    }
    Aw[w][lane] = Ak;
    __syncthreads();
    if (tid < HH) {
        float v = Aw[0][tid] + Aw[1][tid] + Aw[2][tid] + Aw[3][tid];
        atomicAdd(&ws[A_OFF + b*HH + tid], v);
    }

    // ---- last-block fused final ----
    __threadfence();
    __syncthreads();
    if (tid == 0) {
        int old = atomicAdd((int*)(ws + TK_OFF), 1);
        lastf = (old == NBLK3 - 1);
    }
    __syncthreads();
    if (lastf) {
        __threadfence();
        int o = tid & 63, q = tid >> 6;
        int bo = o >> 5, d = o & 31;
        float part = 0.f;
        for (int n = q*128; n < q*128 + 128; n++)
            part += ws[CS_OFF + bo*NN + n] * values[(size_t)(bo*NN + n)*DD + d];
        fin[q*64 + o] = part;
        __syncthreads();
        if (tid < 64) {
            float vsum = fin[o] + fin[64+o] + fin[128+o] + fin[192+o];
            float aw = 0.f;
            #pragma unroll
            for (int k = 0; k < HH; k++) aw += ws[A_OFF + bo*HH + k] * W2[k*DD + d];
            out[o] = 0.5f*b2[d] + 0.5f*aw + 0.5f*vsum;
        }
    }
}

extern "C" void kernel_launch(void* const* d_in, const int* in_sizes, int n_in,
                              void* d_out, int out_size, void* d_ws, size_t ws_size,
                              hipStream_t stream) {
    (void)in_sizes; (void)n_in; (void)out_size; (void)ws_size;
    const float* pos    = (const float*)d_in[0];
    const float* values = (const float*)d_in[1];
    const float* W1     = (const float*)d_in[2];
    const float* b1     = (const float*)d_in[3];
    const float* W2     = (const float*)d_in[4];
    const float* b2     = (const float*)d_in[5];
    const float* Ws1    = (const float*)d_in[6];
    const float* bs1    = (const float*)d_in[7];
    const float* Ws2    = (const float*)d_in[8];
    const float* bs2    = (const float*)d_in[9];
    float* ws  = (float*)d_ws;
    float* out = (float*)d_out;

    prep  <<<(PREP_T + 255)/256, 256, 0, stream>>>(W1, b1, W2, Ws1, ws);
    pass1 <<<NBLK1, 256, 0, stream>>>(pos, values, b2, Ws1, bs1, Ws2, bs2, ws);
    midk  <<<1, 256, 0, stream>>>(ws);
    pass3 <<<NBLK3, 256, 0, stream>>>(pos, values, W1, b1, W2, b2, ws, out);
}

// Round 6
// 46.364 us; speedup vs baseline: 2.5669x; 2.5669x over previous
//
#include <hip/hip_runtime.h>
#include <math.h>

#define BB 2
#define NN 512
#define DD 32
#define HH 64
#define JT 2
#define IPB 2
#define NBLK1 (BB*(NN/IPB)*JT)   // 1024
#define NBLK3 (BB*NN)            // 1024

// ws layout (float offsets)
#define SC_OFF  0                        // scores: B*N*N = 524288
#define MF_OFF  (SC_OFF + BB*NN*NN)      // 0.5*M B-frags: 4096 halves = 2048 fl
#define WF_OFF  (MF_OFF + 2048)          // 0.25*Ws1 B-frags: 2048 halves = 1024 fl
#define W1F_OFF (WF_OFF + 1024)          // W1/b1 A-table: 192 halves (pad 128 fl)
#define PM2_OFF (W1F_OFF + 128)          // per-pass1-block max: 1024
#define PS2_OFF (PM2_OFF + NBLK1)        // per-pass1-block sumexp: 1024
#define ST_OFF  (PS2_OFF + NBLK1)        // per-batch {max, inv_sum}: B*2
#define AP_OFF  (ST_OFF + BB*2)          // A partials: B*N*64 = 65536
#define CS_OFF  (AP_OFF + BB*NN*HH)      // col sums (== row sums): B*N = 1024

typedef _Float16 half8 __attribute__((ext_vector_type(8)));
typedef float    f32x4 __attribute__((ext_vector_type(4)));

__device__ __forceinline__ half8 h8splat(float v) {
    _Float16 h = (_Float16)v;
    half8 r = {h,h,h,h,h,h,h,h};
    return r;
}

__device__ __forceinline__ void invar2(float pix, float piy, float piz,
                                       float pjx, float pjy, float pjz,
                                       float& s, float& cr) {
    s = pix*pjx + piy*pjy + piz*pjz;
    float e12 = pjx*piy - pjy*pix;
    float e13 = pjx*piz - pjz*pix;
    float e23 = pjy*piz - pjz*piy;
    cr = sqrtf(e12*e12 + e13*e13 + e23*e23);
}

// ---------------- prep-lite: fragment tables only ----------------
#define R2 4096                       // M frag halves
#define R3 2048                       // Ws1 frag halves
#define R4 192                        // W1/b1 table halves
#define PREP_T (R2+R3+R4)

__global__ __launch_bounds__(256) void prep(const float* __restrict__ W1,
                                            const float* __restrict__ b1,
                                            const float* __restrict__ W2,
                                            const float* __restrict__ Ws1,
                                            float* __restrict__ ws) {
    int idx = blockIdx.x * 256 + threadIdx.x;
    if (idx < R2) {
        // 0.5*(W2@Ws1) fragment: f=cf*2+kh; lane holds k=kh*32+8*(lane>>4)+t, col=cf*16+(lane&15)
        int e = idx;
        int t = e & 7, lane = (e >> 3) & 63, f = e >> 9;
        int cf = f >> 1, kh = f & 1;
        int k   = kh*32 + 8*(lane >> 4) + t;
        int col = cf*16 + (lane & 15);
        float acc = 0.f;
        #pragma unroll
        for (int d = 0; d < DD; d++) acc += W2[k*DD + d] * Ws1[d*HH + col];
        ((_Float16*)(ws + MF_OFF))[e] = (_Float16)(0.5f * acc);
    } else if (idx < R2+R3) {
        // 0.25*Ws1 fragment (K=32, k=d)
        int e = idx - R2;
        int t = e & 7, lane = (e >> 3) & 63, cf = e >> 9;
        int k   = 8*(lane >> 4) + t;
        int col = cf*16 + (lane & 15);
        ((_Float16*)(ws + WF_OFF))[e] = (_Float16)(0.25f * Ws1[k*HH + col]);
    } else if (idx < R2+R3+R4) {
        // W1/b1 table: e = ((arr*2+kh)*4+g)*8+t, k = kh*32+8g+t
        int e = idx - R2 - R3;
        int t = e & 7, rest = e >> 3;
        int g = rest & 3, kh = (rest >> 2) & 1, arr = rest >> 3;
        int k = kh*32 + 8*g + t;
        float v = (arr == 0) ? W1[k] : (arr == 1) ? W1[HH + k] : b1[k];
        ((_Float16*)(ws + W1F_OFF))[e] = (_Float16)v;
    }
}

// ---------------- pass1: scores via K=96 MFMA + fused softmax partials ----------------
// block = (b, i-pair, jt). 4 waves; wave w owns j in [jt*256+w*64, +64), 2 i rows each.
__global__ __launch_bounds__(256) void pass1(const float* __restrict__ pos,
                                             const float* __restrict__ values,
                                             const float* __restrict__ b2,
                                             const float* __restrict__ Ws1,
                                             const float* __restrict__ bs1,
                                             const float* __restrict__ Ws2,
                                             const float* __restrict__ bs2,
                                             float* __restrict__ ws) {
    __shared__ float uqc[IPB][HH];   // (0.25*v_i + 0.5*b2)@Ws1 + bs1
    __shared__ float ws2l[HH];
    __shared__ float sm4[4], ss4[4];
    int blk = blockIdx.x;
    int jt = blk & 1;
    int ip = (blk >> 1) & 255;
    int b  = blk >> 9;
    int i0 = ip * IPB;
    int tid = threadIdx.x;
    int w    = tid >> 6;
    int lane = tid & 63;
    int g    = lane >> 4;
    int lr   = lane & 15;

    if (tid < IPB*HH) {
        int ii = tid >> 6, l = tid & 63;
        const float* vrow = values + (size_t)(b*NN + i0 + ii)*DD;
        float acc = bs1[l];
        #pragma unroll
        for (int d = 0; d < DD; d++) acc += (0.25f*vrow[d] + 0.5f*b2[d]) * Ws1[d*HH + l];
        uqc[ii][l] = acc;
        if (ii == 0) ws2l[l] = Ws2[l];
    }

    // B fragments from ws (coalesced 16B/lane, L2-hit)
    const half8* mf8 = (const half8*)(ws + MF_OFF);
    const half8* wf8 = (const half8*)(ws + WF_OFF);
    half8 Bf[4][2], Wf[4];
    #pragma unroll
    for (int cf = 0; cf < 4; cf++) {
        Bf[cf][0] = mf8[(cf*2 + 0)*64 + lane];
        Bf[cf][1] = mf8[(cf*2 + 1)*64 + lane];
        Wf[cf]    = wf8[cf*64 + lane];
    }
    const half8* w1f8 = (const half8*)(ws + W1F_OFF);
    half8 W1a[2], W1b[2], B1f[2];
    #pragma unroll
    for (int kh = 0; kh < 2; kh++) {
        W1a[kh] = w1f8[(0*2 + kh)*4 + g];
        W1b[kh] = w1f8[(1*2 + kh)*4 + g];
        B1f[kh] = w1f8[(2*2 + kh)*4 + g];
    }

    float pix[IPB], piy[IPB], piz[IPB];
    #pragma unroll
    for (int ii = 0; ii < IPB; ii++) {
        pix[ii] = pos[(b*NN+i0+ii)*3+0];
        piy[ii] = pos[(b*NN+i0+ii)*3+1];
        piz[ii] = pos[(b*NN+i0+ii)*3+2];
    }
    float bs2v = bs2[0];
    half8 z8 = h8splat(0.f);

    __syncthreads();

    float m_run = -INFINITY, s_run = 0.f;

    #pragma unroll
    for (int rf = 0; rf < 4; rf++) {
        int j_a = jt*256 + w*64 + rf*16 + lr;
        float pjx = pos[(b*NN+j_a)*3+0], pjy = pos[(b*NN+j_a)*3+1], pjz = pos[(b*NN+j_a)*3+2];
        // A2 = f16(values[j_a][8g..8g+8])
        const float* vj = values + (size_t)(b*NN + j_a)*DD + 8*g;
        half8 A2;
        #pragma unroll
        for (int t = 0; t < 8; t++) A2[t] = (_Float16)vj[t];

        #pragma unroll
        for (int ii = 0; ii < IPB; ii++) {
            float s, cr;
            invar2(pix[ii],piy[ii],piz[ii],pjx,pjy,pjz,s,cr);
            half8 s8 = h8splat(s), c8 = h8splat(cr);
            half8 A0 = __builtin_elementwise_max(W1a[0]*s8 + W1b[0]*c8 + B1f[0], z8);
            half8 A1 = __builtin_elementwise_max(W1a[1]*s8 + W1b[1]*c8 + B1f[1], z8);

            f32x4 c[4];
            #pragma unroll
            for (int cf = 0; cf < 4; cf++) {
                f32x4 z = {0.f, 0.f, 0.f, 0.f};
                z = __builtin_amdgcn_mfma_f32_16x16x32_f16(A0, Bf[cf][0], z, 0, 0, 0);
                z = __builtin_amdgcn_mfma_f32_16x16x32_f16(A1, Bf[cf][1], z, 0, 0, 0);
                c[cf] = __builtin_amdgcn_mfma_f32_16x16x32_f16(A2, Wf[cf], z, 0, 0, 0);
            }

            float part0 = 0.f, part1 = 0.f, part2 = 0.f, part3 = 0.f;
            #pragma unroll
            for (int cf = 0; cf < 4; cf++) {
                int lc = cf*16 + lr;
                float base = uqc[ii][lc];
                float w2v  = ws2l[lc];
                part0 += fmaxf(c[cf][0] + base, 0.f) * w2v;
                part1 += fmaxf(c[cf][1] + base, 0.f) * w2v;
                part2 += fmaxf(c[cf][2] + base, 0.f) * w2v;
                part3 += fmaxf(c[cf][3] + base, 0.f) * w2v;
            }
            #pragma unroll
            for (int m = 1; m < 16; m <<= 1) {
                part0 += __shfl_xor(part0, m);
                part1 += __shfl_xor(part1, m);
                part2 += __shfl_xor(part2, m);
                part3 += __shfl_xor(part3, m);
            }
            float x0 = part0 + bs2v, x1 = part1 + bs2v, x2 = part2 + bs2v, x3 = part3 + bs2v;
            if (lr == 0) {
                float4 outv; outv.x = x0; outv.y = x1; outv.z = x2; outv.w = x3;
                *(float4*)(ws + SC_OFF + (size_t)(b*NN + i0 + ii)*NN + jt*256 + w*64 + rf*16 + 4*g) = outv;
            }
            float mm = fmaxf(fmaxf(x0, x1), fmaxf(x2, x3));
            float nm = fmaxf(m_run, mm);
            s_run = s_run*__expf(m_run - nm)
                  + __expf(x0 - nm) + __expf(x1 - nm) + __expf(x2 - nm) + __expf(x3 - nm);
            m_run = nm;
        }
    }

    #pragma unroll
    for (int off = 16; off < 64; off <<= 1) {
        float om = __shfl_xor(m_run, off);
        float os = __shfl_xor(s_run, off);
        float nm = fmaxf(m_run, om);
        s_run = s_run*__expf(m_run - nm) + os*__expf(om - nm);
        m_run = nm;
    }
    if (lane == 0) { sm4[w] = m_run; ss4[w] = s_run; }
    __syncthreads();
    if (tid == 0) {
        float M0 = sm4[0], S0 = ss4[0];
        #pragma unroll
        for (int q = 1; q < 4; q++) {
            float nm = fmaxf(M0, sm4[q]);
            S0 = S0*__expf(M0 - nm) + ss4[q]*__expf(sm4[q] - nm);
            M0 = nm;
        }
        ws[PM2_OFF + blk] = M0;
        ws[PS2_OFF + blk] = S0;
    }
}

// ---------------- midk: reduce 512 partials per batch -> ST ----------------
__global__ __launch_bounds__(256) void midk(float* __restrict__ ws) {
    __shared__ float red[8];
    int tid = threadIdx.x;
    int w = tid >> 6, lane = tid & 63;
    for (int b = 0; b < BB; b++) {
        float m = -INFINITY, s = 0.f;
        #pragma unroll
        for (int q = 0; q < 2; q++) {
            int p = b*512 + tid + q*256;
            float pm = ws[PM2_OFF + p], ps = ws[PS2_OFF + p];
            float nm = fmaxf(m, pm);
            s = s*__expf(m - nm) + ps*__expf(pm - nm);
            m = nm;
        }
        for (int off = 1; off < 64; off <<= 1) {
            float om = __shfl_xor(m, off);
            float os = __shfl_xor(s, off);
            float nm = fmaxf(m, om);
            s = s*__expf(m - nm) + os*__expf(om - nm);
            m = nm;
        }
        if (lane == 0) { red[w*2] = m; red[w*2+1] = s; }
        __syncthreads();
        if (tid == 0) {
            float M0 = red[0], S0 = red[1];
            #pragma unroll
            for (int q = 1; q < 4; q++) {
                float nm = fmaxf(M0, red[q*2]);
                S0 = S0*__expf(M0 - nm) + red[q*2+1]*__expf(red[q*2] - nm);
                M0 = nm;
            }
            ws[ST_OFF + b*2]     = M0;
            ws[ST_OFF + b*2 + 1] = 1.f / S0;
        }
        __syncthreads();
    }
}

// ---------------- pass3: block = (b,i) row; atomic-free partials ----------------
// rowsum == colsum by score symmetry (up to f16 rounding, within tolerance).
__global__ __launch_bounds__(256) void pass3(const float* __restrict__ pos,
                                             const float* __restrict__ W1,
                                             const float* __restrict__ b1,
                                             float* __restrict__ ws) {
    __shared__ float sA[NN], cA[NN], wA[NN];   // 6 KB
    __shared__ float Aw[4][HH];
    __shared__ float rs4[4];
    int blk = blockIdx.x;          // 1024 = B*N
    int b = blk >> 9;
    int i = blk & (NN-1);
    int tid = threadIdx.x;
    int w = tid >> 6, lane = tid & 63;

    float maxv = ws[ST_OFF + b*2], inv = ws[ST_OFF + b*2 + 1];
    float pix = pos[(b*NN+i)*3+0], piy = pos[(b*NN+i)*3+1], piz = pos[(b*NN+i)*3+2];
    const float* sc_row = ws + SC_OFF + (size_t)(b*NN + i)*NN;

    // ---- phase A: pair-parallel wgt/s/cr -> LDS (no atomics) ----
    #pragma unroll
    for (int q = 0; q < 2; q++) {
        int j = tid + q*256;
        float pjx = pos[(b*NN+j)*3+0], pjy = pos[(b*NN+j)*3+1], pjz = pos[(b*NN+j)*3+2];
        float s, cr;
        invar2(pix,piy,piz,pjx,pjy,pjz,s,cr);
        float wgt = __expf(sc_row[j] - maxv) * inv;
        sA[j] = s; cA[j] = cr; wA[j] = wgt;
    }

    // ---- phase B: lane owns k; wave walks 128 pairs with broadcast LDS reads ----
    float w1a = W1[lane], w1b = W1[HH + lane], b1l = b1[lane];
    __syncthreads();
    float Ak = 0.f, rsum = 0.f;
    int p0 = w * 128;
    #pragma unroll 4
    for (int p = p0; p < p0 + 128; p++) {
        float s = sA[p], cr = cA[p], wgt = wA[p];
        float h = fmaxf(fmaf(w1a, s, fmaf(w1b, cr, b1l)), 0.f);
        Ak = fmaf(wgt, h, Ak);
        rsum += wgt;
    }
    Aw[w][lane] = Ak;
    if (lane == 0) rs4[w] = rsum;
    __syncthreads();
    if (tid < HH)
        ws[AP_OFF + ((size_t)(b*NN + i))*HH + tid] = Aw[0][tid] + Aw[1][tid] + Aw[2][tid] + Aw[3][tid];
    if (tid == 0)
        ws[CS_OFF + b*NN + i] = rs4[0] + rs4[1] + rs4[2] + rs4[3];
}

// ---------------- finalk: reduce AP + CS -> out (2 blocks) ----------------
__global__ __launch_bounds__(256) void finalk(const float* __restrict__ values,
                                              const float* __restrict__ W2,
                                              const float* __restrict__ b2,
                                              const float* __restrict__ ws,
                                              float* __restrict__ out) {
    __shared__ float ap4[4][HH];
    __shared__ float vs8[8][DD];
    __shared__ float Ash[HH];
    int b = blockIdx.x;
    int tid = threadIdx.x;

    // A[k] partial over i
    {
        int k = tid & 63, q = tid >> 6;
        const float* ap = ws + AP_OFF + (size_t)b*NN*HH;
        float a = 0.f;
        for (int i = q*128; i < q*128 + 128; i++) a += ap[(size_t)i*HH + k];
        ap4[q][k] = a;
    }
    // vsum[d] partial over n
    {
        int d = tid & 31, q8 = tid >> 5;
        float v = 0.f;
        for (int n = q8*64; n < q8*64 + 64; n++)
            v += ws[CS_OFF + b*NN + n] * values[(size_t)(b*NN + n)*DD + d];
        vs8[q8][d] = v;
    }
    __syncthreads();
    if (tid < HH) Ash[tid] = ap4[0][tid] + ap4[1][tid] + ap4[2][tid] + ap4[3][tid];
    __syncthreads();
    if (tid < DD) {
        float vsum = 0.f;
        #pragma unroll
        for (int q = 0; q < 8; q++) vsum += vs8[q][tid];
        float aw = 0.f;
        #pragma unroll
        for (int k = 0; k < HH; k++) aw += Ash[k] * W2[k*DD + tid];
        out[b*DD + tid] = 0.5f*b2[tid] + 0.5f*aw + 0.5f*vsum;
    }
}

extern "C" void kernel_launch(void* const* d_in, const int* in_sizes, int n_in,
                              void* d_out, int out_size, void* d_ws, size_t ws_size,
                              hipStream_t stream) {
    (void)in_sizes; (void)n_in; (void)out_size; (void)ws_size;
    const float* pos    = (const float*)d_in[0];
    const float* values = (const float*)d_in[1];
    const float* W1     = (const float*)d_in[2];
    const float* b1     = (const float*)d_in[3];
    const float* W2     = (const float*)d_in[4];
    const float* b2     = (const float*)d_in[5];
    const float* Ws1    = (const float*)d_in[6];
    const float* bs1    = (const float*)d_in[7];
    const float* Ws2    = (const float*)d_in[8];
    const float* bs2    = (const float*)d_in[9];
    float* ws  = (float*)d_ws;
    float* out = (float*)d_out;

    prep  <<<(PREP_T + 255)/256, 256, 0, stream>>>(W1, b1, W2, Ws1, ws);
    pass1 <<<NBLK1, 256, 0, stream>>>(pos, values, b2, Ws1, bs1, Ws2, bs2, ws);
    midk  <<<1, 256, 0, stream>>>(ws);
    pass3 <<<NBLK3, 256, 0, stream>>>(pos, W1, b1, ws);
    finalk<<<BB, 256, 0, stream>>>(values, W2, b2, ws, out);
}

// Round 7
// 45.544 us; speedup vs baseline: 2.6132x; 1.0180x over previous
//
#include <hip/hip_runtime.h>
#include <math.h>

#define BB 2
#define NN 512
#define DD 32
#define HH 64
#define JT 2
#define NBLK1 (BB*NN*JT)         // 2048 blocks: (b, i, jt)

// ws layout (float offsets) — no score matrix anymore
#define MF_OFF  0                        // 0.5*M B-frags: 4096 halves = 2048 fl
#define WF_OFF  (MF_OFF + 2048)          // 0.25*Ws1 B-frags: 2048 halves = 1024 fl
#define W1F_OFF (WF_OFF + 1024)          // W1/b1 A-table: 192 halves (pad 128 fl)
#define ST2_OFF (W1F_OFF + 128)          // per-(b,i,jt) {m, s}: 2048*2 = 4096
#define AR_OFF  (ST2_OFF + 4096)         // per-(b,i,jt) Arow[64]: 2048*64 = 131072

typedef _Float16 half8 __attribute__((ext_vector_type(8)));
typedef float    f32x4 __attribute__((ext_vector_type(4)));

__device__ __forceinline__ half8 h8splat(float v) {
    _Float16 h = (_Float16)v;
    half8 r = {h,h,h,h,h,h,h,h};
    return r;
}

__device__ __forceinline__ void invar2(float pix, float piy, float piz,
                                       float pjx, float pjy, float pjz,
                                       float& s, float& cr) {
    s = pix*pjx + piy*pjy + piz*pjz;
    float e12 = pjx*piy - pjy*pix;
    float e13 = pjx*piz - pjz*pix;
    float e23 = pjy*piz - pjz*piy;
    cr = sqrtf(e12*e12 + e13*e13 + e23*e23);
}

// ---------------- prep-lite: fragment tables only ----------------
#define R2 4096                       // M frag halves
#define R3 2048                       // Ws1 frag halves
#define R4 192                        // W1/b1 table halves
#define PREP_T (R2+R3+R4)

__global__ __launch_bounds__(256) void prep(const float* __restrict__ W1,
                                            const float* __restrict__ b1,
                                            const float* __restrict__ W2,
                                            const float* __restrict__ Ws1,
                                            float* __restrict__ ws) {
    int idx = blockIdx.x * 256 + threadIdx.x;
    if (idx < R2) {
        // 0.5*(W2@Ws1) fragment: f=cf*2+kh; lane holds k=kh*32+8*(lane>>4)+t, col=cf*16+(lane&15)
        int e = idx;
        int t = e & 7, lane = (e >> 3) & 63, f = e >> 9;
        int cf = f >> 1, kh = f & 1;
        int k   = kh*32 + 8*(lane >> 4) + t;
        int col = cf*16 + (lane & 15);
        float acc = 0.f;
        #pragma unroll
        for (int d = 0; d < DD; d++) acc += W2[k*DD + d] * Ws1[d*HH + col];
        ((_Float16*)(ws + MF_OFF))[e] = (_Float16)(0.5f * acc);
    } else if (idx < R2+R3) {
        // 0.25*Ws1 fragment (K=32, k=d)
        int e = idx - R2;
        int t = e & 7, lane = (e >> 3) & 63, cf = e >> 9;
        int k   = 8*(lane >> 4) + t;
        int col = cf*16 + (lane & 15);
        ((_Float16*)(ws + WF_OFF))[e] = (_Float16)(0.25f * Ws1[k*HH + col]);
    } else if (idx < R2+R3+R4) {
        // W1/b1 table: e = ((arr*2+kh)*4+g)*8+t, k = kh*32+8g+t
        int e = idx - R2 - R3;
        int t = e & 7, rest = e >> 3;
        int g = rest & 3, kh = (rest >> 2) & 1, arr = rest >> 3;
        int k = kh*32 + 8*g + t;
        float v = (arr == 0) ? W1[k] : (arr == 1) ? W1[HH + k] : b1[k];
        ((_Float16*)(ws + W1F_OFF))[e] = (_Float16)v;
    }
}

// ---------------- pass1: fused scores + online softmax + online A accumulation ----------------
// block = (b, i, jt). 4 waves; wave w owns j in [jt*256+w*64, +64).
// Outputs per block: ST2 = (m, s) and AR[64] = sum_j exp(x_j - m) * h_k(i,j)  (base m).
__global__ __launch_bounds__(256) void pass1(const float* __restrict__ pos,
                                             const float* __restrict__ values,
                                             const float* __restrict__ b2,
                                             const float* __restrict__ Ws1,
                                             const float* __restrict__ bs1,
                                             const float* __restrict__ Ws2,
                                             const float* __restrict__ bs2,
                                             float* __restrict__ ws) {
    __shared__ float uqc[HH];        // (0.25*v_i + 0.5*b2)@Ws1 + bs1
    __shared__ float ws2l[HH];
    __shared__ float lA[4][HH];      // per-wave Arow partial
    __shared__ float lms[4][2];      // per-wave (m, s)
    int blk = blockIdx.x;
    int jt = blk & 1;
    int i  = (blk >> 1) & (NN-1);
    int b  = blk >> 10;
    int tid = threadIdx.x;
    int w    = tid >> 6;
    int lane = tid & 63;
    int g    = lane >> 4;
    int lr   = lane & 15;

    if (tid < HH) {
        const float* vrow = values + (size_t)(b*NN + i)*DD;
        float acc = bs1[tid];
        #pragma unroll
        for (int d = 0; d < DD; d++) acc += (0.25f*vrow[d] + 0.5f*b2[d]) * Ws1[d*HH + tid];
        uqc[tid]  = acc;
        ws2l[tid] = Ws2[tid];
    }

    // B fragments from ws (coalesced 16B/lane, L2-hit)
    const half8* mf8 = (const half8*)(ws + MF_OFF);
    const half8* wf8 = (const half8*)(ws + WF_OFF);
    half8 Bf[4][2], Wf[4];
    #pragma unroll
    for (int cf = 0; cf < 4; cf++) {
        Bf[cf][0] = mf8[(cf*2 + 0)*64 + lane];
        Bf[cf][1] = mf8[(cf*2 + 1)*64 + lane];
        Wf[cf]    = wf8[cf*64 + lane];
    }
    const half8* w1f8 = (const half8*)(ws + W1F_OFF);
    half8 W1a[2], W1b[2], B1f[2];
    #pragma unroll
    for (int kh = 0; kh < 2; kh++) {
        W1a[kh] = w1f8[(0*2 + kh)*4 + g];
        W1b[kh] = w1f8[(1*2 + kh)*4 + g];
        B1f[kh] = w1f8[(2*2 + kh)*4 + g];
    }

    float pix = pos[(b*NN+i)*3+0], piy = pos[(b*NN+i)*3+1], piz = pos[(b*NN+i)*3+2];
    float bs2v = bs2[0];
    half8 z8 = h8splat(0.f);

    __syncthreads();

    float m_run = -INFINITY, s_run = 0.f;
    float Ak[16];
    #pragma unroll
    for (int t = 0; t < 16; t++) Ak[t] = 0.f;

    #pragma unroll
    for (int rf = 0; rf < 4; rf++) {
        int j_a = jt*256 + w*64 + rf*16 + lr;
        float pjx = pos[(b*NN+j_a)*3+0], pjy = pos[(b*NN+j_a)*3+1], pjz = pos[(b*NN+j_a)*3+2];
        // A2 = f16(values[j_a][8g..8g+8])
        const float* vj = values + (size_t)(b*NN + j_a)*DD + 8*g;
        half8 A2;
        #pragma unroll
        for (int t = 0; t < 8; t++) A2[t] = (_Float16)vj[t];

        float s, cr;
        invar2(pix,piy,piz,pjx,pjy,pjz,s,cr);
        half8 s8 = h8splat(s), c8 = h8splat(cr);
        half8 A0 = __builtin_elementwise_max(W1a[0]*s8 + W1b[0]*c8 + B1f[0], z8);
        half8 A1 = __builtin_elementwise_max(W1a[1]*s8 + W1b[1]*c8 + B1f[1], z8);

        f32x4 c[4];
        #pragma unroll
        for (int cf = 0; cf < 4; cf++) {
            f32x4 z = {0.f, 0.f, 0.f, 0.f};
            z = __builtin_amdgcn_mfma_f32_16x16x32_f16(A0, Bf[cf][0], z, 0, 0, 0);
            z = __builtin_amdgcn_mfma_f32_16x16x32_f16(A1, Bf[cf][1], z, 0, 0, 0);
            c[cf] = __builtin_amdgcn_mfma_f32_16x16x32_f16(A2, Wf[cf], z, 0, 0, 0);
        }

        float part0 = 0.f, part1 = 0.f, part2 = 0.f, part3 = 0.f;
        #pragma unroll
        for (int cf = 0; cf < 4; cf++) {
            int lc = cf*16 + lr;
            float base = uqc[lc];
            float w2v  = ws2l[lc];
            part0 += fmaxf(c[cf][0] + base, 0.f) * w2v;
            part1 += fmaxf(c[cf][1] + base, 0.f) * w2v;
            part2 += fmaxf(c[cf][2] + base, 0.f) * w2v;
            part3 += fmaxf(c[cf][3] + base, 0.f) * w2v;
        }
        #pragma unroll
        for (int m = 1; m < 16; m <<= 1) {
            part0 += __shfl_xor(part0, m);
            part1 += __shfl_xor(part1, m);
            part2 += __shfl_xor(part2, m);
            part3 += __shfl_xor(part3, m);
        }
        // group-uniform scores for rows 4g+0..3
        float x0 = part0 + bs2v, x1 = part1 + bs2v, x2 = part2 + bs2v, x3 = part3 + bs2v;

        // fetch own row's score (row = lr, held by group lr>>2, component lr&3)
        int src = (lr >> 2) << 4;
        float y0 = __shfl(x0, src);
        float y1 = __shfl(x1, src);
        float y2 = __shfl(x2, src);
        float y3 = __shfl(x3, src);
        float t01 = (lr & 1) ? y1 : y0;
        float t23 = (lr & 1) ? y3 : y2;
        float x_own = (lr & 2) ? t23 : t01;

        // online merge
        float mm = fmaxf(fmaxf(x0, x1), fmaxf(x2, x3));
        float nm = fmaxf(m_run, mm);
        float rsc = __expf(m_run - nm);
        s_run = s_run*rsc
              + __expf(x0 - nm) + __expf(x1 - nm) + __expf(x2 - nm) + __expf(x3 - nm);
        float w_own = __expf(x_own - nm);
        #pragma unroll
        for (int t = 0; t < 8; t++) Ak[t]   = fmaf(Ak[t],   rsc, w_own * (float)A0[t]);
        #pragma unroll
        for (int t = 0; t < 8; t++) Ak[8+t] = fmaf(Ak[8+t], rsc, w_own * (float)A1[t]);
        m_run = nm;
    }

    // cross-group (m,s) merge (lr-duplicates identical within group)
    float mg = m_run;
    #pragma unroll
    for (int off = 16; off < 64; off <<= 1) {
        float om = __shfl_xor(m_run, off);
        float os = __shfl_xor(s_run, off);
        float nm = fmaxf(m_run, om);
        s_run = s_run*__expf(m_run - nm) + os*__expf(om - nm);
        m_run = nm;
    }
    // lr-butterfly reduce of Ak (within group; same base mg)
    #pragma unroll
    for (int t = 0; t < 16; t++) {
        #pragma unroll
        for (int msk = 1; msk < 16; msk <<= 1) Ak[t] += __shfl_xor(Ak[t], msk);
    }
    float gsc = __expf(mg - m_run);   // rebase group partial to wave max
    if (lr == 0) {
        #pragma unroll
        for (int t = 0; t < 8; t++) lA[w][8*g + t]      = Ak[t]   * gsc;
        #pragma unroll
        for (int t = 0; t < 8; t++) lA[w][32 + 8*g + t] = Ak[8+t] * gsc;
    }
    if (lane == 0) { lms[w][0] = m_run; lms[w][1] = s_run; }
    __syncthreads();

    // block merge of 4 wave partials -> global store
    if (tid < HH) {
        float m0 = lms[0][0], m1 = lms[1][0], m2 = lms[2][0], m3 = lms[3][0];
        float mB = fmaxf(fmaxf(m0, m1), fmaxf(m2, m3));
        float e0 = __expf(m0 - mB), e1 = __expf(m1 - mB);
        float e2 = __expf(m2 - mB), e3 = __expf(m3 - mB);
        float ar = lA[0][tid]*e0 + lA[1][tid]*e1 + lA[2][tid]*e2 + lA[3][tid]*e3;
        ws[AR_OFF + (size_t)blk*HH + tid] = ar;
        if (tid == 0) {
            float sB = lms[0][1]*e0 + lms[1][1]*e1 + lms[2][1]*e2 + lms[3][1]*e3;
            ws[ST2_OFF + blk*2]     = mB;
            ws[ST2_OFF + blk*2 + 1] = sB;
        }
    }
}

// ---------------- finalk: global softmax reduce + combine (one block per batch) ----------------
__global__ __launch_bounds__(256) void finalk(const float* __restrict__ values,
                                              const float* __restrict__ W2,
                                              const float* __restrict__ b2,
                                              const float* __restrict__ ws,
                                              float* __restrict__ out) {
    __shared__ float red[8];
    __shared__ float MS[2];
    __shared__ float wf[NN*JT];    // 4 KB
    __shared__ float csh[NN];      // 2 KB
    __shared__ float vs8[8][DD];
    __shared__ float as4[4][HH];
    __shared__ float Ash[HH];
    int b = blockIdx.x;
    int tid = threadIdx.x;
    int w = tid >> 6, lane = tid & 63;
    const float* st2 = ws + ST2_OFF + (size_t)b*NN*JT*2;   // 1024 (m,s) pairs

    // phase 1: global (M, S)
    {
        float m = -INFINITY, s = 0.f;
        #pragma unroll
        for (int q = 0; q < 4; q++) {
            int p = tid + q*256;
            float pm = st2[p*2], ps = st2[p*2+1];
            float nm = fmaxf(m, pm);
            s = s*__expf(m - nm) + ps*__expf(pm - nm);
            m = nm;
        }
        for (int off = 1; off < 64; off <<= 1) {
            float om = __shfl_xor(m, off);
            float os = __shfl_xor(s, off);
            float nm = fmaxf(m, om);
            s = s*__expf(m - nm) + os*__expf(om - nm);
            m = nm;
        }
        if (lane == 0) { red[w*2] = m; red[w*2+1] = s; }
    }
    __syncthreads();
    if (tid == 0) {
        float M0 = red[0], S0 = red[1];
        #pragma unroll
        for (int q = 1; q < 4; q++) {
            float nm = fmaxf(M0, red[q*2]);
            S0 = S0*__expf(M0 - nm) + red[q*2+1]*__expf(red[q*2] - nm);
            M0 = nm;
        }
        MS[0] = M0; MS[1] = 1.f / S0;
    }
    __syncthreads();
    float M = MS[0], invS = MS[1];

    // phase 2: per-segment weights wf[p] = exp(m_p - M) / S
    #pragma unroll
    for (int q = 0; q < 4; q++) {
        int p = tid + q*256;
        wf[p] = __expf(st2[p*2] - M) * invS;
    }
    __syncthreads();
    // cs_i = sum_jt s_p * wf[p]   (row sums == col sums by symmetry)
    #pragma unroll
    for (int q = 0; q < 2; q++) {
        int i = tid + q*256;
        csh[i] = st2[(2*i)*2+1]*wf[2*i] + st2[(2*i+1)*2+1]*wf[2*i+1];
    }
    __syncthreads();

    // vsum[d] = sum_i cs_i * v[i][d]
    {
        int d = tid & 31, sl = tid >> 5;
        float v = 0.f;
        for (int i = sl*64; i < sl*64 + 64; i++)
            v += csh[i] * values[(size_t)(b*NN + i)*DD + d];
        vs8[sl][d] = v;
    }
    // A[k] = sum_p AR[p][k] * wf[p]
    {
        int k = tid & 63, sl = tid >> 6;
        const float* ar = ws + AR_OFF + (size_t)b*NN*JT*HH;
        float a = 0.f;
        for (int p = sl*256; p < sl*256 + 256; p++)
            a += ar[(size_t)p*HH + k] * wf[p];
        as4[sl][k] = a;
    }
    __syncthreads();
    if (tid < HH) Ash[tid] = as4[0][tid] + as4[1][tid] + as4[2][tid] + as4[3][tid];
    __syncthreads();
    if (tid < DD) {
        float vsum = 0.f;
        #pragma unroll
        for (int q = 0; q < 8; q++) vsum += vs8[q][tid];
        float aw = 0.f;
        #pragma unroll
        for (int k = 0; k < HH; k++) aw += Ash[k] * W2[k*DD + tid];
        out[b*DD + tid] = 0.5f*b2[tid] + 0.5f*aw + 0.5f*vsum;
    }
}

extern "C" void kernel_launch(void* const* d_in, const int* in_sizes, int n_in,
                              void* d_out, int out_size, void* d_ws, size_t ws_size,
                              hipStream_t stream) {
    (void)in_sizes; (void)n_in; (void)out_size; (void)ws_size;
    const float* pos    = (const float*)d_in[0];
    const float* values = (const float*)d_in[1];
    const float* W1     = (const float*)d_in[2];
    const float* b1     = (const float*)d_in[3];
    const float* W2     = (const float*)d_in[4];
    const float* b2     = (const float*)d_in[5];
    const float* Ws1    = (const float*)d_in[6];
    const float* bs1    = (const float*)d_in[7];
    const float* Ws2    = (const float*)d_in[8];
    const float* bs2    = (const float*)d_in[9];
    float* ws  = (float*)d_ws;
    float* out = (float*)d_out;

    prep  <<<(PREP_T + 255)/256, 256, 0, stream>>>(W1, b1, W2, Ws1, ws);
    pass1 <<<NBLK1, 256, 0, stream>>>(pos, values, b2, Ws1, bs1, Ws2, bs2, ws);
    finalk<<<BB, 256, 0, stream>>>(values, W2, b2, ws, out);
}

// Round 8
// 44.283 us; speedup vs baseline: 2.6875x; 1.0285x over previous
//
#include <hip/hip_runtime.h>
#include <math.h>

#define BB 2
#define NN 512
#define DD 32
#define HH 64
#define JT 2
#define NBLK1 (BB*NN*JT)         // 2048 blocks: (b, i, jt)

// ws layout (float offsets)
#define MF_OFF  0                        // 0.5*M B-frags: 4096 halves = 2048 fl
#define WF_OFF  (MF_OFF + 2048)          // 0.25*Ws1 B-frags: 2048 halves = 1024 fl
#define W1F_OFF (WF_OFF + 1024)          // W1/b1 A-table: 192 halves (pad 128 fl)
#define UQC_OFF (W1F_OFF + 128)          // uqc[b][n][l]: B*N*64 = 65536
#define ST2_OFF (UQC_OFF + BB*NN*HH)     // per-(b,i,jt) {m, s}: 2048*2 = 4096
#define AR_OFF  (ST2_OFF + 4096)         // per-(b,i,jt) Arow[64]: 2048*64 = 131072

typedef _Float16 half8 __attribute__((ext_vector_type(8)));
typedef float    f32x4 __attribute__((ext_vector_type(4)));

__device__ __forceinline__ half8 h8splat(float v) {
    _Float16 h = (_Float16)v;
    half8 r = {h,h,h,h,h,h,h,h};
    return r;
}

__device__ __forceinline__ void invar2(float pix, float piy, float piz,
                                       float pjx, float pjy, float pjz,
                                       float& s, float& cr) {
    s = pix*pjx + piy*pjy + piz*pjz;
    float e12 = pjx*piy - pjy*pix;
    float e13 = pjx*piz - pjz*pix;
    float e23 = pjy*piz - pjz*piy;
    cr = sqrtf(e12*e12 + e13*e13 + e23*e23);
}

// ---------------- prep: fragment tables + uqc table ----------------
#define R2 4096                       // M frag halves
#define R3 2048                       // Ws1 frag halves
#define R4 192                        // W1/b1 table halves
#define R5 (BB*NN*HH)                 // uqc entries
#define PREP_T (R2+R3+R4+R5)

__global__ __launch_bounds__(256) void prep(const float* __restrict__ values,
                                            const float* __restrict__ W1,
                                            const float* __restrict__ b1,
                                            const float* __restrict__ W2,
                                            const float* __restrict__ b2,
                                            const float* __restrict__ Ws1,
                                            const float* __restrict__ bs1,
                                            float* __restrict__ ws) {
    int idx = blockIdx.x * 256 + threadIdx.x;
    if (idx < R2) {
        // 0.5*(W2@Ws1) fragment: f=cf*2+kh; lane holds k=kh*32+8*(lane>>4)+t, col=cf*16+(lane&15)
        int e = idx;
        int t = e & 7, lane = (e >> 3) & 63, f = e >> 9;
        int cf = f >> 1, kh = f & 1;
        int k   = kh*32 + 8*(lane >> 4) + t;
        int col = cf*16 + (lane & 15);
        float acc = 0.f;
        #pragma unroll
        for (int d = 0; d < DD; d++) acc += W2[k*DD + d] * Ws1[d*HH + col];
        ((_Float16*)(ws + MF_OFF))[e] = (_Float16)(0.5f * acc);
    } else if (idx < R2+R3) {
        // 0.25*Ws1 fragment (K=32, k=d)
        int e = idx - R2;
        int t = e & 7, lane = (e >> 3) & 63, cf = e >> 9;
        int k   = 8*(lane >> 4) + t;
        int col = cf*16 + (lane & 15);
        ((_Float16*)(ws + WF_OFF))[e] = (_Float16)(0.25f * Ws1[k*HH + col]);
    } else if (idx < R2+R3+R4) {
        // W1/b1 table: e = ((arr*2+kh)*4+g)*8+t, k = kh*32+8g+t
        int e = idx - R2 - R3;
        int t = e & 7, rest = e >> 3;
        int g = rest & 3, kh = (rest >> 2) & 1, arr = rest >> 3;
        int k = kh*32 + 8*g + t;
        float v = (arr == 0) ? W1[k] : (arr == 1) ? W1[HH + k] : b1[k];
        ((_Float16*)(ws + W1F_OFF))[e] = (_Float16)v;
    } else if (idx < PREP_T) {
        // uqc[b][n][l] = bs1[l] + sum_d (0.25*v[b][n][d] + 0.5*b2[d]) * Ws1[d][l]
        int e = idx - R2 - R3 - R4;
        int l = e & 63; int n = (e >> 6) & (NN-1); int b = e >> 15;
        const float* vrow = values + (size_t)(b*NN + n)*DD;
        float acc = bs1[l];
        #pragma unroll
        for (int d = 0; d < DD; d++) acc += (0.25f*vrow[d] + 0.5f*b2[d]) * Ws1[d*HH + l];
        ws[UQC_OFF + e] = acc;
    }
}

// ---------------- pass1: 3-phase fused scores + softmax partials + A partials ----------------
// block = (b, i, jt). 4 waves; wave w owns local j in [w*64, w*64+64).
__global__ __launch_bounds__(256) void pass1(const float* __restrict__ pos,
                                             const float* __restrict__ values,
                                             const float* __restrict__ W1,
                                             const float* __restrict__ b1,
                                             const float* __restrict__ Ws2,
                                             const float* __restrict__ bs2,
                                             float* __restrict__ ws) {
    __shared__ float uqc[HH];
    __shared__ float ws2l[HH];
    __shared__ float sc[256];        // raw scores, then overwritten by weights
    __shared__ float sA[256], cA[256];
    __shared__ float lms[4][2];
    __shared__ float Aw[4][HH];
    int blk = blockIdx.x;
    int jt = blk & 1;
    int i  = (blk >> 1) & (NN-1);
    int b  = blk >> 10;
    int tid = threadIdx.x;
    int w    = tid >> 6;
    int lane = tid & 63;
    int g    = lane >> 4;
    int lr   = lane & 15;

    if (tid < HH) {
        uqc[tid]  = ws[UQC_OFF + ((size_t)(b*NN + i))*HH + tid];
        ws2l[tid] = Ws2[tid];
    }

    // B fragments from ws (coalesced 16B/lane, L2-hit)
    const half8* mf8 = (const half8*)(ws + MF_OFF);
    const half8* wf8 = (const half8*)(ws + WF_OFF);
    half8 Bf[4][2], Wf[4];
    #pragma unroll
    for (int cf = 0; cf < 4; cf++) {
        Bf[cf][0] = mf8[(cf*2 + 0)*64 + lane];
        Bf[cf][1] = mf8[(cf*2 + 1)*64 + lane];
        Wf[cf]    = wf8[cf*64 + lane];
    }
    const half8* w1f8 = (const half8*)(ws + W1F_OFF);
    half8 W1a[2], W1b[2], B1f[2];
    #pragma unroll
    for (int kh = 0; kh < 2; kh++) {
        W1a[kh] = w1f8[(0*2 + kh)*4 + g];
        W1b[kh] = w1f8[(1*2 + kh)*4 + g];
        B1f[kh] = w1f8[(2*2 + kh)*4 + g];
    }

    float pix = pos[(b*NN+i)*3+0], piy = pos[(b*NN+i)*3+1], piz = pos[(b*NN+i)*3+2];
    float bs2v = bs2[0];
    half8 z8 = h8splat(0.f);

    __syncthreads();

    // ---- phase 1: scores -> LDS + per-wave online (m,s) ----
    float m_run = -INFINITY, s_run = 0.f;

    #pragma unroll
    for (int rf = 0; rf < 4; rf++) {
        int jl  = w*64 + rf*16 + lr;          // local j
        int j_a = jt*256 + jl;                // global j
        float pjx = pos[(b*NN+j_a)*3+0], pjy = pos[(b*NN+j_a)*3+1], pjz = pos[(b*NN+j_a)*3+2];
        const float* vj = values + (size_t)(b*NN + j_a)*DD + 8*g;
        float4 va = *(const float4*)(vj);
        float4 vb = *(const float4*)(vj + 4);
        half8 A2;
        A2[0]=(_Float16)va.x; A2[1]=(_Float16)va.y; A2[2]=(_Float16)va.z; A2[3]=(_Float16)va.w;
        A2[4]=(_Float16)vb.x; A2[5]=(_Float16)vb.y; A2[6]=(_Float16)vb.z; A2[7]=(_Float16)vb.w;

        float s, cr;
        invar2(pix,piy,piz,pjx,pjy,pjz,s,cr);
        if (g == 0) { sA[jl] = s; cA[jl] = cr; }
        half8 s8 = h8splat(s), c8 = h8splat(cr);
        half8 A0 = __builtin_elementwise_max(W1a[0]*s8 + W1b[0]*c8 + B1f[0], z8);
        half8 A1 = __builtin_elementwise_max(W1a[1]*s8 + W1b[1]*c8 + B1f[1], z8);

        f32x4 c[4];
        #pragma unroll
        for (int cf = 0; cf < 4; cf++) {
            f32x4 z = {0.f, 0.f, 0.f, 0.f};
            z = __builtin_amdgcn_mfma_f32_16x16x32_f16(A0, Bf[cf][0], z, 0, 0, 0);
            z = __builtin_amdgcn_mfma_f32_16x16x32_f16(A1, Bf[cf][1], z, 0, 0, 0);
            c[cf] = __builtin_amdgcn_mfma_f32_16x16x32_f16(A2, Wf[cf], z, 0, 0, 0);
        }

        float part0 = 0.f, part1 = 0.f, part2 = 0.f, part3 = 0.f;
        #pragma unroll
        for (int cf = 0; cf < 4; cf++) {
            int lc = cf*16 + lr;
            float base = uqc[lc];
            float w2v  = ws2l[lc];
            part0 += fmaxf(c[cf][0] + base, 0.f) * w2v;
            part1 += fmaxf(c[cf][1] + base, 0.f) * w2v;
            part2 += fmaxf(c[cf][2] + base, 0.f) * w2v;
            part3 += fmaxf(c[cf][3] + base, 0.f) * w2v;
        }
        #pragma unroll
        for (int m = 1; m < 16; m <<= 1) {
            part0 += __shfl_xor(part0, m);
            part1 += __shfl_xor(part1, m);
            part2 += __shfl_xor(part2, m);
            part3 += __shfl_xor(part3, m);
        }
        // group-uniform scores x0..x3 = rows 4g+0..3 of this rf
        float x0 = part0 + bs2v, x1 = part1 + bs2v, x2 = part2 + bs2v, x3 = part3 + bs2v;

        // write raw scores: lanes lr<4 write row 4g+lr
        float xs01 = (lr & 1) ? x1 : x0;
        float xs23 = (lr & 1) ? x3 : x2;
        float xsel = (lr & 2) ? xs23 : xs01;
        if (lr < 4) sc[w*64 + rf*16 + 4*g + lr] = xsel;

        // online (m,s) over the 4 rows
        float mm = fmaxf(fmaxf(x0, x1), fmaxf(x2, x3));
        float nm = fmaxf(m_run, mm);
        s_run = s_run*__expf(m_run - nm)
              + __expf(x0 - nm) + __expf(x1 - nm) + __expf(x2 - nm) + __expf(x3 - nm);
        m_run = nm;
    }

    // cross-group (m,s) merge
    #pragma unroll
    for (int off = 16; off < 64; off <<= 1) {
        float om = __shfl_xor(m_run, off);
        float os = __shfl_xor(s_run, off);
        float nm = fmaxf(m_run, om);
        s_run = s_run*__expf(m_run - nm) + os*__expf(om - nm);
        m_run = nm;
    }
    if (lane == 0) { lms[w][0] = m_run; lms[w][1] = s_run; }
    __syncthreads();

    // ---- phase 2: block (mB, sB); weights = exp(sc - mB) ----
    float m0 = lms[0][0], m1 = lms[1][0], m2 = lms[2][0], m3 = lms[3][0];
    float mB = fmaxf(fmaxf(m0, m1), fmaxf(m2, m3));
    float sB = lms[0][1]*__expf(m0 - mB) + lms[1][1]*__expf(m1 - mB)
             + lms[2][1]*__expf(m2 - mB) + lms[3][1]*__expf(m3 - mB);
    sc[tid] = __expf(sc[tid] - mB);
    __syncthreads();

    // ---- phase 3: lane-owns-k accumulation over this wave's 64 j ----
    float w1a = W1[lane], w1b = W1[HH + lane], b1l = b1[lane];
    float Ak = 0.f;
    int p0 = w * 64;
    #pragma unroll 4
    for (int p = p0; p < p0 + 64; p++) {
        float s = sA[p], cr = cA[p], wgt = sc[p];
        float h = fmaxf(fmaf(w1a, s, fmaf(w1b, cr, b1l)), 0.f);
        Ak = fmaf(wgt, h, Ak);
    }
    Aw[w][lane] = Ak;
    __syncthreads();

    if (tid < HH)
        ws[AR_OFF + (size_t)blk*HH + tid] = Aw[0][tid] + Aw[1][tid] + Aw[2][tid] + Aw[3][tid];
    if (tid == 0) {
        ws[ST2_OFF + blk*2]     = mB;
        ws[ST2_OFF + blk*2 + 1] = sB;
    }
}

// ---------------- finalk: global softmax reduce + combine (one block per batch) ----------------
__global__ __launch_bounds__(256) void finalk(const float* __restrict__ values,
                                              const float* __restrict__ W2,
                                              const float* __restrict__ b2,
                                              const float* __restrict__ ws,
                                              float* __restrict__ out) {
    __shared__ float red[8];
    __shared__ float MS[2];
    __shared__ float wf[NN*JT];    // 4 KB
    __shared__ float csh[NN];      // 2 KB
    __shared__ float vs8[8][DD];
    __shared__ float as4[4][HH];
    __shared__ float Ash[HH];
    int b = blockIdx.x;
    int tid = threadIdx.x;
    int w = tid >> 6, lane = tid & 63;
    const float* st2 = ws + ST2_OFF + (size_t)b*NN*JT*2;   // 1024 (m,s) pairs

    // phase 1: global (M, S)
    {
        float m = -INFINITY, s = 0.f;
        #pragma unroll
        for (int q = 0; q < 4; q++) {
            int p = tid + q*256;
            float pm = st2[p*2], ps = st2[p*2+1];
            float nm = fmaxf(m, pm);
            s = s*__expf(m - nm) + ps*__expf(pm - nm);
            m = nm;
        }
        for (int off = 1; off < 64; off <<= 1) {
            float om = __shfl_xor(m, off);
            float os = __shfl_xor(s, off);
            float nm = fmaxf(m, om);
            s = s*__expf(m - nm) + os*__expf(om - nm);
            m = nm;
        }
        if (lane == 0) { red[w*2] = m; red[w*2+1] = s; }
    }
    __syncthreads();
    if (tid == 0) {
        float M0 = red[0], S0 = red[1];
        #pragma unroll
        for (int q = 1; q < 4; q++) {
            float nm = fmaxf(M0, red[q*2]);
            S0 = S0*__expf(M0 - nm) + red[q*2+1]*__expf(red[q*2] - nm);
            M0 = nm;
        }
        MS[0] = M0; MS[1] = 1.f / S0;
    }
    __syncthreads();
    float M = MS[0], invS = MS[1];

    // phase 2: per-segment weights wf[p] = exp(m_p - M) / S
    #pragma unroll
    for (int q = 0; q < 4; q++) {
        int p = tid + q*256;
        wf[p] = __expf(st2[p*2] - M) * invS;
    }
    __syncthreads();
    // cs_i = sum_jt s_p * wf[p]   (row sums == col sums by symmetry)
    #pragma unroll
    for (int q = 0; q < 2; q++) {
        int i = tid + q*256;
        csh[i] = st2[(2*i)*2+1]*wf[2*i] + st2[(2*i+1)*2+1]*wf[2*i+1];
    }
    __syncthreads();

    // vsum[d] = sum_i cs_i * v[i][d]
    {
        int d = tid & 31, sl = tid >> 5;
        float v = 0.f;
        for (int i = sl*64; i < sl*64 + 64; i++)
            v += csh[i] * values[(size_t)(b*NN + i)*DD + d];
        vs8[sl][d] = v;
    }
    // A[k] = sum_p AR[p][k] * wf[p]
    {
        int k = tid & 63, sl = tid >> 6;
        const float* ar = ws + AR_OFF + (size_t)b*NN*JT*HH;
        float a = 0.f;
        for (int p = sl*256; p < sl*256 + 256; p++)
            a += ar[(size_t)p*HH + k] * wf[p];
        as4[sl][k] = a;
    }
    __syncthreads();
    if (tid < HH) Ash[tid] = as4[0][tid] + as4[1][tid] + as4[2][tid] + as4[3][tid];
    __syncthreads();
    if (tid < DD) {
        float vsum = 0.f;
        #pragma unroll
        for (int q = 0; q < 8; q++) vsum += vs8[q][tid];
        float aw = 0.f;
        #pragma unroll
        for (int k = 0; k < HH; k++) aw += Ash[k] * W2[k*DD + tid];
        out[b*DD + tid] = 0.5f*b2[tid] + 0.5f*aw + 0.5f*vsum;
    }
}

extern "C" void kernel_launch(void* const* d_in, const int* in_sizes, int n_in,
                              void* d_out, int out_size, void* d_ws, size_t ws_size,
                              hipStream_t stream) {
    (void)in_sizes; (void)n_in; (void)out_size; (void)ws_size;
    const float* pos    = (const float*)d_in[0];
    const float* values = (const float*)d_in[1];
    const float* W1     = (const float*)d_in[2];
    const float* b1     = (const float*)d_in[3];
    const float* W2     = (const float*)d_in[4];
    const float* b2     = (const float*)d_in[5];
    const float* Ws1    = (const float*)d_in[6];
    const float* bs1    = (const float*)d_in[7];
    const float* Ws2    = (const float*)d_in[8];
    const float* bs2    = (const float*)d_in[9];
    float* ws  = (float*)d_ws;
    float* out = (float*)d_out;

    prep  <<<(PREP_T + 255)/256, 256, 0, stream>>>(values, W1, b1, W2, b2, Ws1, bs1, ws);
    pass1 <<<NBLK1, 256, 0, stream>>>(pos, values, W1, b1, Ws2, bs2, ws);
    finalk<<<BB, 256, 0, stream>>>(values, W2, b2, ws, out);
}

// Round 9
// 42.902 us; speedup vs baseline: 2.7741x; 1.0322x over previous
//
#include <hip/hip_runtime.h>
#include <math.h>

#define BB 2
#define NN 512
#define DD 32
#define HH 64
#define JT 2
#define NBLK1 (BB*NN*JT)         // 2048 blocks: (b, i, jt)

// ws layout (float offsets)
#define MF_OFF  0                        // 0.5*M^T A-frags: lt(4)*kh(2)*64*8 = 4096 halves = 2048 fl
#define WF_OFF  (MF_OFF + 2048)          // 0.25*Ws1^T A-frags: lt(4)*64*8 = 2048 halves = 1024 fl
#define W1F_OFF (WF_OFF + 1024)          // W1/b1 B-side table: 192 halves (pad 128 fl)
#define ST2_OFF (W1F_OFF + 128)          // per-(b,i,jt) {m, s}: 2048*2 = 4096
#define AR_OFF  (ST2_OFF + 4096)         // per-(b,i,jt) Arow[64]: 2048*64 = 131072

typedef _Float16 half8 __attribute__((ext_vector_type(8)));
typedef float    f32x4 __attribute__((ext_vector_type(4)));

__device__ __forceinline__ half8 h8splat(float v) {
    _Float16 h = (_Float16)v;
    half8 r = {h,h,h,h,h,h,h,h};
    return r;
}

__device__ __forceinline__ void invar2(float pix, float piy, float piz,
                                       float pjx, float pjy, float pjz,
                                       float& s, float& cr) {
    s = pix*pjx + piy*pjy + piz*pjz;
    float e12 = pjx*piy - pjy*pix;
    float e13 = pjx*piz - pjz*pix;
    float e23 = pjy*piz - pjz*piy;
    cr = sqrtf(e12*e12 + e13*e13 + e23*e23);
}

// ---------------- prep: A-side fragment tables (transposed roles) ----------------
#define R2 4096                       // 0.5*M^T frag halves
#define R3 2048                       // 0.25*Ws1^T frag halves
#define R4 192                        // W1/b1 table halves
#define PREP_T (R2+R3+R4)

__global__ __launch_bounds__(256) void prep(const float* __restrict__ W1,
                                            const float* __restrict__ b1,
                                            const float* __restrict__ W2,
                                            const float* __restrict__ Ws1,
                                            float* __restrict__ ws) {
    int idx = blockIdx.x * 256 + threadIdx.x;
    if (idx < R2) {
        // A-frag for h-GEMM: frag f = lt*2+kh; lane holds A[row=l][k],
        // l = lt*16 + (lane&15), k = kh*32 + 8*(lane>>4) + t; value = 0.5*M[k][l], M = W2@Ws1
        int e = idx;
        int t = e & 7, lane = (e >> 3) & 63, f = e >> 9;
        int lt = f >> 1, kh = f & 1;
        int k = kh*32 + 8*(lane >> 4) + t;
        int l = lt*16 + (lane & 15);
        float acc = 0.f;
        #pragma unroll
        for (int d = 0; d < DD; d++) acc += W2[k*DD + d] * Ws1[d*HH + l];
        ((_Float16*)(ws + MF_OFF))[e] = (_Float16)(0.5f * acc);
    } else if (idx < R2+R3) {
        // A-frag for v-GEMM: frag lt; lane holds A[row=l][d], d = 8*(lane>>4)+t,
        // l = lt*16+(lane&15); value = 0.25*Ws1[d][l]
        int e = idx - R2;
        int t = e & 7, lane = (e >> 3) & 63, lt = e >> 9;
        int d = 8*(lane >> 4) + t;
        int l = lt*16 + (lane & 15);
        ((_Float16*)(ws + WF_OFF))[e] = (_Float16)(0.25f * Ws1[d*HH + l]);
    } else if (idx < R2+R3+R4) {
        // W1/b1 table: e = ((arr*2+kh)*4+g)*8+t, k = kh*32+8g+t
        int e = idx - R2 - R3;
        int t = e & 7, rest = e >> 3;
        int g = rest & 3, kh = (rest >> 2) & 1, arr = rest >> 3;
        int k = kh*32 + 8*g + t;
        float v = (arr == 0) ? W1[k] : (arr == 1) ? W1[HH + k] : b1[k];
        ((_Float16*)(ws + W1F_OFF))[e] = (_Float16)v;
    }
}

// ---------------- pass1: swapped-operand scores, lane-owns-j, DS-minimal ----------------
// block = (b, i, jt). 4 waves; wave w owns j in [jt*256+w*64, +64); lane (g,lr): j = ..+rf*16+lr.
__global__ __launch_bounds__(256, 2) void pass1(const float* __restrict__ pos,
                                                const float* __restrict__ values,
                                                const float* __restrict__ b2,
                                                const float* __restrict__ bs1,
                                                const float* __restrict__ Ws2,
                                                const float* __restrict__ bs2,
                                                float* __restrict__ ws) {
    __shared__ float lms[4][2];
    __shared__ float Aw[4][HH];
    int blk = blockIdx.x;
    int jt = blk & 1;
    int i  = (blk >> 1) & (NN-1);
    int b  = blk >> 10;
    int tid = threadIdx.x;
    int w    = tid >> 6;
    int lane = tid & 63;
    int g    = lane >> 4;
    int lr   = lane & 15;

    // A-side fragments (global, L2-hit, coalesced 16B/lane)
    const half8* mf8 = (const half8*)(ws + MF_OFF);
    const half8* wf8 = (const half8*)(ws + WF_OFF);
    half8 AfM[4][2], AfW[4];
    #pragma unroll
    for (int lt = 0; lt < 4; lt++) {
        AfM[lt][0] = mf8[(lt*2 + 0)*64 + lane];
        AfM[lt][1] = mf8[(lt*2 + 1)*64 + lane];
        AfW[lt]    = wf8[lt*64 + lane];
    }
    const half8* w1f8 = (const half8*)(ws + W1F_OFF);
    half8 W1a[2], W1b[2], B1f[2];
    #pragma unroll
    for (int kh = 0; kh < 2; kh++) {
        W1a[kh] = w1f8[(0*2 + kh)*4 + g];
        W1b[kh] = w1f8[(1*2 + kh)*4 + g];
        B1f[kh] = w1f8[(2*2 + kh)*4 + g];
    }

    // per-lane l-vectors: l = lt*16 + 4g + r
    float ws2g[16], bs1g[16];
    #pragma unroll
    for (int lt = 0; lt < 4; lt++)
        #pragma unroll
        for (int r = 0; r < 4; r++) {
            int l = lt*16 + 4*g + r;
            ws2g[lt*4+r] = Ws2[l];
            bs1g[lt*4+r] = bs1[l];
        }

    // viplus[d] = v_i[d] + 2*b2[d] for the lane's d-slice (d = 8g+t)
    float vip[8];
    {
        const float* vi = values + (size_t)(b*NN + i)*DD + 8*g;
        float4 a = *(const float4*)vi;
        float4 c = *(const float4*)(vi + 4);
        const float* b2s = b2 + 8*g;
        float4 ba = *(const float4*)b2s;
        float4 bc = *(const float4*)(b2s + 4);
        vip[0]=a.x+2.f*ba.x; vip[1]=a.y+2.f*ba.y; vip[2]=a.z+2.f*ba.z; vip[3]=a.w+2.f*ba.w;
        vip[4]=c.x+2.f*bc.x; vip[5]=c.y+2.f*bc.y; vip[6]=c.z+2.f*bc.z; vip[7]=c.w+2.f*bc.w;
    }

    float pix = pos[(b*NN+i)*3+0], piy = pos[(b*NN+i)*3+1], piz = pos[(b*NN+i)*3+2];
    float bs2v = bs2[0];
    half8 z8 = h8splat(0.f);

    half8 bh0[4], bh1[4];     // retained h (B-operand) per rf
    float x[4];               // lane's own scores
    float m_l = -INFINITY, s_l = 0.f;

    #pragma unroll
    for (int rf = 0; rf < 4; rf++) {
        int j = jt*256 + w*64 + rf*16 + lr;
        float pjx = pos[(b*NN+j)*3+0], pjy = pos[(b*NN+j)*3+1], pjz = pos[(b*NN+j)*3+2];
        float s, cr;
        invar2(pix,piy,piz,pjx,pjy,pjz,s,cr);
        half8 s8 = h8splat(s), c8 = h8splat(cr);
        bh0[rf] = __builtin_elementwise_max(W1a[0]*s8 + W1b[0]*c8 + B1f[0], z8);
        bh1[rf] = __builtin_elementwise_max(W1a[1]*s8 + W1b[1]*c8 + B1f[1], z8);

        // B-operand v-part: v_j + viplus, f16
        const float* vj = values + (size_t)(b*NN + j)*DD + 8*g;
        float4 va = *(const float4*)vj;
        float4 vb = *(const float4*)(vj + 4);
        half8 Bv;
        Bv[0]=(_Float16)(va.x+vip[0]); Bv[1]=(_Float16)(va.y+vip[1]);
        Bv[2]=(_Float16)(va.z+vip[2]); Bv[3]=(_Float16)(va.w+vip[3]);
        Bv[4]=(_Float16)(vb.x+vip[4]); Bv[5]=(_Float16)(vb.y+vip[5]);
        Bv[6]=(_Float16)(vb.z+vip[6]); Bv[7]=(_Float16)(vb.w+vip[7]);

        // pre^T[l][j]: 4 l-tiles, acc init = bs1
        float xp = 0.f;
        #pragma unroll
        for (int lt = 0; lt < 4; lt++) {
            f32x4 c = {bs1g[lt*4+0], bs1g[lt*4+1], bs1g[lt*4+2], bs1g[lt*4+3]};
            c = __builtin_amdgcn_mfma_f32_16x16x32_f16(AfM[lt][0], bh0[rf], c, 0, 0, 0);
            c = __builtin_amdgcn_mfma_f32_16x16x32_f16(AfM[lt][1], bh1[rf], c, 0, 0, 0);
            c = __builtin_amdgcn_mfma_f32_16x16x32_f16(AfW[lt],    Bv,      c, 0, 0, 0);
            xp += fmaxf(c[0], 0.f)*ws2g[lt*4+0];
            xp += fmaxf(c[1], 0.f)*ws2g[lt*4+1];
            xp += fmaxf(c[2], 0.f)*ws2g[lt*4+2];
            xp += fmaxf(c[3], 0.f)*ws2g[lt*4+3];
        }
        // sum over the 4 g-groups (each held 16 of 64 l's)
        xp += __shfl_xor(xp, 16);
        xp += __shfl_xor(xp, 32);
        float xs = xp + bs2v;
        x[rf] = xs;
        // per-lane online (m,s) over own scores
        float nm = fmaxf(m_l, xs);
        s_l = s_l*__expf(m_l - nm) + __expf(xs - nm);
        m_l = nm;
    }

    // wave (m,s): merge 16 lr slots (g-dups identical)
    #pragma unroll
    for (int off = 1; off < 16; off <<= 1) {
        float om = __shfl_xor(m_l, off);
        float os = __shfl_xor(s_l, off);
        float nm = fmaxf(m_l, om);
        s_l = s_l*__expf(m_l - nm) + os*__expf(om - nm);
        m_l = nm;
    }
    if (lane == 0) { lms[w][0] = m_l; lms[w][1] = s_l; }
    __syncthreads();

    // block stats
    float m0 = lms[0][0], m1 = lms[1][0], m2 = lms[2][0], m3 = lms[3][0];
    float mB = fmaxf(fmaxf(m0, m1), fmaxf(m2, m3));
    float sB = lms[0][1]*__expf(m0 - mB) + lms[1][1]*__expf(m1 - mB)
             + lms[2][1]*__expf(m2 - mB) + lms[3][1]*__expf(m3 - mB);
    if (tid == 0) {
        ws[ST2_OFF + blk*2]     = mB;
        ws[ST2_OFF + blk*2 + 1] = sB;
    }

    // phase 3: lane accumulates A over its own 4 j's for its 16 k's (k = kh*32+8g+t)
    float Ak[16];
    #pragma unroll
    for (int t = 0; t < 16; t++) Ak[t] = 0.f;
    #pragma unroll
    for (int rf = 0; rf < 4; rf++) {
        float wgt = __expf(x[rf] - mB);
        #pragma unroll
        for (int t = 0; t < 8; t++) {
            Ak[t]   = fmaf(wgt, (float)bh0[rf][t], Ak[t]);
            Ak[8+t] = fmaf(wgt, (float)bh1[rf][t], Ak[8+t]);
        }
    }
    // reduce over the 16 lr lanes
    #pragma unroll
    for (int t = 0; t < 16; t++) {
        #pragma unroll
        for (int off = 1; off < 16; off <<= 1) Ak[t] += __shfl_xor(Ak[t], off);
    }
    if (lr == 0) {
        #pragma unroll
        for (int t = 0; t < 8; t++) {
            Aw[w][8*g + t]      = Ak[t];
            Aw[w][32 + 8*g + t] = Ak[8+t];
        }
    }
    __syncthreads();
    if (tid < HH)
        ws[AR_OFF + (size_t)blk*HH + tid] = Aw[0][tid] + Aw[1][tid] + Aw[2][tid] + Aw[3][tid];
}

// ---------------- finalk: global softmax reduce + combine (one block per batch) ----------------
__global__ __launch_bounds__(256) void finalk(const float* __restrict__ values,
                                              const float* __restrict__ W2,
                                              const float* __restrict__ b2,
                                              const float* __restrict__ ws,
                                              float* __restrict__ out) {
    __shared__ float red[8];
    __shared__ float MS[2];
    __shared__ float wf[NN*JT];    // 4 KB
    __shared__ float csh[NN];      // 2 KB
    __shared__ float vs8[8][DD];
    __shared__ float as4[4][HH];
    __shared__ float Ash[HH];
    int b = blockIdx.x;
    int tid = threadIdx.x;
    int w = tid >> 6, lane = tid & 63;
    const float* st2 = ws + ST2_OFF + (size_t)b*NN*JT*2;   // 1024 (m,s) pairs

    // phase 1: global (M, S)
    {
        float m = -INFINITY, s = 0.f;
        #pragma unroll
        for (int q = 0; q < 4; q++) {
            int p = tid + q*256;
            float pm = st2[p*2], ps = st2[p*2+1];
            float nm = fmaxf(m, pm);
            s = s*__expf(m - nm) + ps*__expf(pm - nm);
            m = nm;
        }
        for (int off = 1; off < 64; off <<= 1) {
            float om = __shfl_xor(m, off);
            float os = __shfl_xor(s, off);
            float nm = fmaxf(m, om);
            s = s*__expf(m - nm) + os*__expf(om - nm);
            m = nm;
        }
        if (lane == 0) { red[w*2] = m; red[w*2+1] = s; }
    }
    __syncthreads();
    if (tid == 0) {
        float M0 = red[0], S0 = red[1];
        #pragma unroll
        for (int q = 1; q < 4; q++) {
            float nm = fmaxf(M0, red[q*2]);
            S0 = S0*__expf(M0 - nm) + red[q*2+1]*__expf(red[q*2] - nm);
            M0 = nm;
        }
        MS[0] = M0; MS[1] = 1.f / S0;
    }
    __syncthreads();
    float M = MS[0], invS = MS[1];

    // phase 2: per-segment weights wf[p] = exp(m_p - M) / S
    #pragma unroll
    for (int q = 0; q < 4; q++) {
        int p = tid + q*256;
        wf[p] = __expf(st2[p*2] - M) * invS;
    }
    __syncthreads();
    // cs_i = sum_jt s_p * wf[p]   (row sums == col sums by symmetry)
    #pragma unroll
    for (int q = 0; q < 2; q++) {
        int i = tid + q*256;
        csh[i] = st2[(2*i)*2+1]*wf[2*i] + st2[(2*i+1)*2+1]*wf[2*i+1];
    }
    __syncthreads();

    // vsum[d] = sum_i cs_i * v[i][d]
    {
        int d = tid & 31, sl = tid >> 5;
        float v = 0.f;
        for (int i = sl*64; i < sl*64 + 64; i++)
            v += csh[i] * values[(size_t)(b*NN + i)*DD + d];
        vs8[sl][d] = v;
    }
    // A[k] = sum_p AR[p][k] * wf[p]
    {
        int k = tid & 63, sl = tid >> 6;
        const float* ar = ws + AR_OFF + (size_t)b*NN*JT*HH;
        float a = 0.f;
        for (int p = sl*256; p < sl*256 + 256; p++)
            a += ar[(size_t)p*HH + k] * wf[p];
        as4[sl][k] = a;
    }
    __syncthreads();
    if (tid < HH) Ash[tid] = as4[0][tid] + as4[1][tid] + as4[2][tid] + as4[3][tid];
    __syncthreads();
    if (tid < DD) {
        float vsum = 0.f;
        #pragma unroll
        for (int q = 0; q < 8; q++) vsum += vs8[q][tid];
        float aw = 0.f;
        #pragma unroll
        for (int k = 0; k < HH; k++) aw += Ash[k] * W2[k*DD + tid];
        out[b*DD + tid] = 0.5f*b2[tid] + 0.5f*aw + 0.5f*vsum;
    }
}

extern "C" void kernel_launch(void* const* d_in, const int* in_sizes, int n_in,
                              void* d_out, int out_size, void* d_ws, size_t ws_size,
                              hipStream_t stream) {
    (void)in_sizes; (void)n_in; (void)out_size; (void)ws_size;
    const float* pos    = (const float*)d_in[0];
    const float* values = (const float*)d_in[1];
    const float* W1     = (const float*)d_in[2];
    const float* b1     = (const float*)d_in[3];
    const float* W2     = (const float*)d_in[4];
    const float* b2     = (const float*)d_in[5];
    const float* Ws1    = (const float*)d_in[6];
    const float* bs1    = (const float*)d_in[7];
    const float* Ws2    = (const float*)d_in[8];
    const float* bs2    = (const float*)d_in[9];
    float* ws  = (float*)d_ws;
    float* out = (float*)d_out;

    prep  <<<(PREP_T + 255)/256, 256, 0, stream>>>(W1, b1, W2, Ws1, ws);
    pass1 <<<NBLK1, 256, 0, stream>>>(pos, values, b2, bs1, Ws2, bs2, ws);
    finalk<<<BB, 256, 0, stream>>>(values, W2, b2, ws, out);
}